// Round 1
// baseline (547.429 us; speedup 1.0000x reference)
//
#include <hip/hip_runtime.h>

#define PP 399
#define BB 256

// ---------------------------------------------------------------------------
// Locally-connected conv1d (K=5, pad 2) + ReLU + maxpool(10, stride 3) fused,
// streamed per (b, p) column. One thread per (b,p).
//
// in  : [B][CIN][TIN][PP]
// Wt  : [PP][3][CIN][5]
// Bs  : [PP][3]
// out : [B][<outBstride>] with element (b, co, j, p) at
//       out[b*outBstride + co*(TOUT*PP) + j*PP + p]
//
// Pool state machine: conv output tau; window j covers tau in [3j, 3j+9].
// At tau%3==0 (group jg, tau=3jg): emit window jg-3 = max(m1, c); rotate:
//   m1 <- max(m2,c); m2 <- max(m3,c); m3 <- c.
// Else: m1,m2,m3 <- max(., c). Only 3 live max registers per channel.
// ---------------------------------------------------------------------------
template<int CIN, int TIN, int TOUT>
__global__ __launch_bounds__(256)
void conv_pool_kernel(const float* __restrict__ in,
                      const float* __restrict__ Wt,
                      const float* __restrict__ Bs,
                      float* __restrict__ out,
                      int outBstride)
{
    int gid = blockIdx.x * 256 + threadIdx.x;
    if (gid >= BB * PP) return;
    int b = gid / PP;
    int p = gid - b * PP;

    // per-position weights -> registers
    float w[3][CIN][5];
    const float* wp = Wt + (long)p * (3 * CIN * 5);
#pragma unroll
    for (int co = 0; co < 3; ++co)
#pragma unroll
        for (int ci = 0; ci < CIN; ++ci)
#pragma unroll
            for (int k = 0; k < 5; ++k)
                w[co][ci][k] = wp[(co * CIN + ci) * 5 + k];

    float bias[3];
#pragma unroll
    for (int co = 0; co < 3; ++co) bias[co] = Bs[(long)p * 3 + co];

    const float* inp = in + (long)b * CIN * TIN * PP + p;
    float* outp = out + (long)b * outBstride + p;

    // input shift registers; window for conv at tau holds inputs tau-2..tau+2
    float xw[CIN][5];
#pragma unroll
    for (int ci = 0; ci < CIN; ++ci) {
#pragma unroll
        for (int k = 0; k < 5; ++k) xw[ci][k] = 0.f;
        // pre-state = inputs {-3,-2,-1,0,1}; first step loads input 2
        xw[ci][3] = inp[(long)ci * TIN * PP + 0];
        xw[ci][4] = inp[(long)ci * TIN * PP + 1 * PP];
    }

    float m1[3], m2[3], m3[3];
#pragma unroll
    for (int co = 0; co < 3; ++co) { m1[co] = -1e30f; m2[co] = -1e30f; m3[co] = -1e30f; }

    for (int jg = 0; jg < TOUT + 3; ++jg) {
#pragma unroll
        for (int phi = 0; phi < 3; ++phi) {
            int tau = 3 * jg + phi;
            int tload = tau + 2;
            float nv[CIN];
#pragma unroll
            for (int ci = 0; ci < CIN; ++ci)
                nv[ci] = (tload < TIN) ? inp[(long)ci * TIN * PP + (long)tload * PP] : 0.f;
            // shift
#pragma unroll
            for (int ci = 0; ci < CIN; ++ci) {
                xw[ci][0] = xw[ci][1];
                xw[ci][1] = xw[ci][2];
                xw[ci][2] = xw[ci][3];
                xw[ci][3] = xw[ci][4];
                xw[ci][4] = nv[ci];
            }
            // conv + relu
            float c[3];
#pragma unroll
            for (int co = 0; co < 3; ++co) {
                float acc = bias[co];
#pragma unroll
                for (int ci = 0; ci < CIN; ++ci)
#pragma unroll
                    for (int k = 0; k < 5; ++k)
                        acc = fmaf(xw[ci][k], w[co][ci][k], acc);
                c[co] = fmaxf(acc, 0.f);
            }
            if (phi == 0) {
#pragma unroll
                for (int co = 0; co < 3; ++co) {
                    float e = fmaxf(m1[co], c[co]);
                    m1[co] = fmaxf(m2[co], c[co]);
                    m2[co] = fmaxf(m3[co], c[co]);
                    m3[co] = c[co];
                    if (jg >= 3)
                        outp[(long)co * (TOUT * PP) + (long)(jg - 3) * PP] = e;
                }
            } else {
#pragma unroll
                for (int co = 0; co < 3; ++co) {
                    m1[co] = fmaxf(m1[co], c[co]);
                    m2[co] = fmaxf(m2[co], c[co]);
                    m3[co] = fmaxf(m3[co], c[co]);
                }
            }
        }
    }
}

// ---------------------------------------------------------------------------
// out[m, c] = act( sum_k A[m,k] * W[k,c] + bias[c] )
// thread -> column c, TM rows per thread. A loads are wave-uniform (s_load),
// W loads coalesced across c.
// ---------------------------------------------------------------------------
template<int TM>
__global__ __launch_bounds__(256)
void linear_kernel(const float* __restrict__ A,   // [M][K]
                   const float* __restrict__ Wt,  // [K][N]
                   const float* __restrict__ bias,// [N]
                   float* __restrict__ out,       // [M][outStride]
                   int K, int N, int outStride, int do_relu)
{
    int c = blockIdx.x * 256 + threadIdx.x;
    if (c >= N) return;
    int m0 = blockIdx.y * TM;

    float acc[TM];
#pragma unroll
    for (int i = 0; i < TM; ++i) acc[i] = 0.f;

#pragma unroll 8
    for (int k = 0; k < K; ++k) {
        float wv = Wt[(long)k * N + c];
#pragma unroll
        for (int i = 0; i < TM; ++i)
            acc[i] = fmaf(A[(long)(m0 + i) * K + k], wv, acc[i]);
    }

    float bv = bias[c];
#pragma unroll
    for (int i = 0; i < TM; ++i) {
        float v = acc[i] + bv;
        if (do_relu) v = fmaxf(v, 0.f);
        out[(long)(m0 + i) * outStride + c] = v;
    }
}

// out[m] = sum_k c3[m,k]*fW[k] + fb
__global__ __launch_bounds__(64)
void final_kernel(const float* __restrict__ c3,
                  const float* __restrict__ fW,
                  const float* __restrict__ fb,
                  float* __restrict__ out)
{
    int m = blockIdx.x * 64 + threadIdx.x;
    if (m >= BB) return;
    float acc = fb[0];
#pragma unroll
    for (int k = 0; k < 20; ++k)
        acc = fmaf(c3[m * 20 + k], fW[k], acc);
    out[m] = acc;
}

extern "C" void kernel_launch(void* const* d_in, const int* in_sizes, int n_in,
                              void* d_out, int out_size, void* d_ws, size_t ws_size,
                              hipStream_t stream)
{
    const float* x   = (const float*)d_in[0];   // [256,365,399]
    const float* x2  = (const float*)d_in[1];   // [256,1307]
    const float* W1  = (const float*)d_in[2];
    const float* b1  = (const float*)d_in[3];
    const float* W2  = (const float*)d_in[4];
    const float* b2  = (const float*)d_in[5];
    const float* W3  = (const float*)d_in[6];
    const float* b3  = (const float*)d_in[7];
    const float* W4  = (const float*)d_in[8];
    const float* b4  = (const float*)d_in[9];
    const float* lW1 = (const float*)d_in[10];
    const float* lb1 = (const float*)d_in[11];
    const float* lW2 = (const float*)d_in[12];
    const float* lb2 = (const float*)d_in[13];
    const float* lW3 = (const float*)d_in[14];
    const float* lb3 = (const float*)d_in[15];
    const float* cW1 = (const float*)d_in[16];
    const float* cb1 = (const float*)d_in[17];
    const float* cW2 = (const float*)d_in[18];
    const float* cb2 = (const float*)d_in[19];
    const float* cW3 = (const float*)d_in[20];
    const float* cb3 = (const float*)d_in[21];
    const float* fW  = (const float*)d_in[22];
    const float* fb  = (const float*)d_in[23];
    float* out = (float*)d_out;

    // workspace layout (floats)
    float* ws = (float*)d_ws;
    const long n_h1   = (long)BB * 3 * 119 * PP;   // 36,636,672
    const long n_h2   = (long)BB * 3 * 37 * PP;    // 11,390,976
    const long n_h3   = (long)BB * 3 * 10 * PP;    //  3,078,912
    const long n_cbuf = (long)BB * 1297;           //    332,032
    float* h1   = ws;
    float* h2   = h1 + n_h1;
    float* h3   = h2 + n_h2;
    float* cbuf = h3 + n_h3;
    float* e1   = cbuf + n_cbuf;        // [256,700]
    float* e2   = e1 + (long)BB * 700;  // [256,200]
    float* c1   = e2 + (long)BB * 200;  // [256,500]
    float* c2   = c1 + (long)BB * 500;  // [256,100]
    float* c3b  = c2 + (long)BB * 100;  // [256,20]

    const int nblk = (BB * PP) / 256;   // 399 exactly

    // conv stages
    conv_pool_kernel<1, 365, 119><<<nblk, 256, 0, stream>>>(x,  W1, b1, h1, 3 * 119 * PP);
    conv_pool_kernel<3, 119,  37><<<nblk, 256, 0, stream>>>(h1, W2, b2, h2, 3 * 37 * PP);
    conv_pool_kernel<3,  37,  10><<<nblk, 256, 0, stream>>>(h2, W3, b3, h3, 3 * 10 * PP);
    // stage 4 writes enc1 straight into the concat buffer: cbuf[b, co*399+p]
    conv_pool_kernel<3,  10,   1><<<nblk, 256, 0, stream>>>(h3, W4, b4, cbuf, 1297);

    // enc2 path
    linear_kernel<4><<<dim3(3, 64), 256, 0, stream>>>(x2, lW1, lb1, e1, 1307, 700, 700, 1);
    linear_kernel<4><<<dim3(1, 64), 256, 0, stream>>>(e1, lW2, lb2, e2, 700, 200, 200, 1);
    // enc2 -> cbuf columns [1197, 1297)
    linear_kernel<4><<<dim3(1, 64), 256, 0, stream>>>(e2, lW3, lb3, cbuf + 1197, 200, 100, 1297, 0);

    // combined head
    linear_kernel<4><<<dim3(2, 64), 256, 0, stream>>>(cbuf, cW1, cb1, c1, 1297, 500, 500, 1);
    linear_kernel<4><<<dim3(1, 64), 256, 0, stream>>>(c1, cW2, cb2, c2, 500, 100, 100, 1);
    linear_kernel<4><<<dim3(1, 64), 256, 0, stream>>>(c2, cW3, cb3, c3b, 100, 20, 20, 1);

    final_kernel<<<dim3((BB + 63) / 64), 64, 0, stream>>>(c3b, fW, fb, out);
}

// Round 2
// 303.656 us; speedup vs baseline: 1.8028x; 1.8028x over previous
//
#include <hip/hip_runtime.h>

#define PP 399
#define BB 256

// ---------------------------------------------------------------------------
// Locally-connected conv1d (K=5, pad 2) + ReLU + maxpool(10, stride 3) fused,
// streamed per (b, p) column. One thread per (b,p). T-segmented via blockIdx.y:
// segment handles output windows [j0, j1).
// in  : [B][CIN][TIN][PP];  Wt: [PP][3][CIN][5];  Bs: [PP][3]
// out : (b, co, j, p) at out[b*outBstride + co*(TOUT*PP) + j*PP + p]
// ---------------------------------------------------------------------------
template<int CIN, int TIN, int TOUT>
__global__ __launch_bounds__(256)
void conv_pool_kernel(const float* __restrict__ in,
                      const float* __restrict__ Wt,
                      const float* __restrict__ Bs,
                      float* __restrict__ out,
                      int outBstride, int L)
{
    int gid = blockIdx.x * 256 + threadIdx.x;
    if (gid >= BB * PP) return;
    int b = gid / PP;
    int p = gid - b * PP;
    int j0 = blockIdx.y * L;
    int j1 = min(TOUT, j0 + L);

    float w[3][CIN][5];
    const float* wp = Wt + (long)p * (3 * CIN * 5);
#pragma unroll
    for (int co = 0; co < 3; ++co)
#pragma unroll
        for (int ci = 0; ci < CIN; ++ci)
#pragma unroll
            for (int k = 0; k < 5; ++k)
                w[co][ci][k] = wp[(co * CIN + ci) * 5 + k];

    float bias[3];
#pragma unroll
    for (int co = 0; co < 3; ++co) bias[co] = Bs[(long)p * 3 + co];

    const float* inp = in + (long)b * CIN * TIN * PP + p;
    float* outp = out + (long)b * outBstride + p;

    // shift register preloaded with taus {3j0-3 .. 3j0+1}
    float xw[CIN][5];
#pragma unroll
    for (int ci = 0; ci < CIN; ++ci) {
#pragma unroll
        for (int k = 0; k < 5; ++k) {
            int t = 3 * j0 - 3 + k;
            xw[ci][k] = (t >= 0 && t < TIN) ? inp[(long)ci * TIN * PP + (long)t * PP] : 0.f;
        }
    }

    float m1[3], m2[3], m3[3];
#pragma unroll
    for (int co = 0; co < 3; ++co) { m1[co] = -1e30f; m2[co] = -1e30f; m3[co] = -1e30f; }

    for (int jg = j0; jg < j1 + 3; ++jg) {
#pragma unroll
        for (int phi = 0; phi < 3; ++phi) {
            int tau = 3 * jg + phi;
            int tload = tau + 2;
            float nv[CIN];
#pragma unroll
            for (int ci = 0; ci < CIN; ++ci)
                nv[ci] = (tload < TIN) ? inp[(long)ci * TIN * PP + (long)tload * PP] : 0.f;
#pragma unroll
            for (int ci = 0; ci < CIN; ++ci) {
                xw[ci][0] = xw[ci][1];
                xw[ci][1] = xw[ci][2];
                xw[ci][2] = xw[ci][3];
                xw[ci][3] = xw[ci][4];
                xw[ci][4] = nv[ci];
            }
            float c[3];
#pragma unroll
            for (int co = 0; co < 3; ++co) {
                float acc = bias[co];
#pragma unroll
                for (int ci = 0; ci < CIN; ++ci)
#pragma unroll
                    for (int k = 0; k < 5; ++k)
                        acc = fmaf(xw[ci][k], w[co][ci][k], acc);
                c[co] = fmaxf(acc, 0.f);
            }
            if (phi == 0) {
#pragma unroll
                for (int co = 0; co < 3; ++co) {
                    float e = fmaxf(m1[co], c[co]);
                    m1[co] = fmaxf(m2[co], c[co]);
                    m2[co] = fmaxf(m3[co], c[co]);
                    m3[co] = c[co];
                    if (jg >= j0 + 3)
                        outp[(long)co * (TOUT * PP) + (long)(jg - 3) * PP] = e;
                }
            } else {
#pragma unroll
                for (int co = 0; co < 3; ++co) {
                    m1[co] = fmaxf(m1[co], c[co]);
                    m2[co] = fmaxf(m2[co], c[co]);
                    m3[co] = fmaxf(m3[co], c[co]);
                }
            }
        }
    }
}

// ---------------------------------------------------------------------------
// Split-K GEMM with f32 atomic accumulation. out must be pre-seeded with bias.
// A: [256][lda] (optionally relu'd on load), Wt: [K][N], out: [256][ldo].
// Block: 32(M)x32(N) tile, BK=32, K-chunk = kchunk per blockIdx.z.
// Thread: row ty=tid/8, cols tx4=(tid%8)*4 .. +3.
// ---------------------------------------------------------------------------
template<int RELU_A>
__global__ __launch_bounds__(256)
void gemm_atomic(const float* __restrict__ A,
                 const float* __restrict__ Wt,
                 float* __restrict__ out,
                 int K, int N, int lda, int ldo, int kchunk)
{
    __shared__ float As[32][36];
    __shared__ float Bs[32][36];

    int tid = threadIdx.x;
    int ty  = tid >> 3;         // 0..31
    int tx4 = (tid & 7) * 4;    // 0,4,...,28
    int c0 = blockIdx.x * 32;
    int m0 = blockIdx.y * 32;
    int k0 = blockIdx.z * kchunk;
    int klim = min(K, k0 + kchunk);

    float4 acc = make_float4(0.f, 0.f, 0.f, 0.f);

    for (int kb = k0; kb < klim; kb += 32) {
        // stage A tile: row m0+ty, ks kb+tx4..+3
#pragma unroll
        for (int j = 0; j < 4; ++j) {
            int kk = kb + tx4 + j;
            float v = (kk < klim) ? A[(long)(m0 + ty) * lda + kk] : 0.f;
            if (RELU_A) v = fmaxf(v, 0.f);
            As[ty][tx4 + j] = v;
        }
        // stage B tile: k-row kb+ty, cols c0+tx4..+3
#pragma unroll
        for (int j = 0; j < 4; ++j) {
            int kk = kb + ty;
            int c = c0 + tx4 + j;
            Bs[ty][tx4 + j] = (kk < klim && c < N) ? Wt[(long)kk * N + c] : 0.f;
        }
        __syncthreads();
#pragma unroll
        for (int kk = 0; kk < 32; ++kk) {
            float a = As[ty][kk];
            float4 bv = *(const float4*)&Bs[kk][tx4];
            acc.x = fmaf(a, bv.x, acc.x);
            acc.y = fmaf(a, bv.y, acc.y);
            acc.z = fmaf(a, bv.z, acc.z);
            acc.w = fmaf(a, bv.w, acc.w);
        }
        __syncthreads();
    }

    long m = m0 + ty;
    if (c0 + tx4 + 0 < N) atomicAdd(&out[m * ldo + c0 + tx4 + 0], acc.x);
    if (c0 + tx4 + 1 < N) atomicAdd(&out[m * ldo + c0 + tx4 + 1], acc.y);
    if (c0 + tx4 + 2 < N) atomicAdd(&out[m * ldo + c0 + tx4 + 2], acc.z);
    if (c0 + tx4 + 3 < N) atomicAdd(&out[m * ldo + c0 + tx4 + 3], acc.w);
}

// Seed all linear-layer output buffers with their biases (atomic GEMMs add on top).
__global__ __launch_bounds__(256)
void init_bias(float* __restrict__ e1, const float* __restrict__ lb1,
               float* __restrict__ e2, const float* __restrict__ lb2,
               float* __restrict__ enc2, const float* __restrict__ lb3,  // cbuf+1197, ldo 1297
               float* __restrict__ c1, const float* __restrict__ cb1,
               float* __restrict__ c2, const float* __restrict__ cb2,
               float* __restrict__ c3, const float* __restrict__ cb3)
{
    int idx = blockIdx.x * 256 + threadIdx.x;
    if (idx < BB * 700) { e1[idx] = lb1[idx % 700]; return; }
    idx -= BB * 700;
    if (idx < BB * 200) { e2[idx] = lb2[idx % 200]; return; }
    idx -= BB * 200;
    if (idx < BB * 100) { int m = idx / 100, c = idx % 100; enc2[(long)m * 1297 + c] = lb3[c]; return; }
    idx -= BB * 100;
    if (idx < BB * 500) { c1[idx] = cb1[idx % 500]; return; }
    idx -= BB * 500;
    if (idx < BB * 100) { c2[idx] = cb2[idx % 100]; return; }
    idx -= BB * 100;
    if (idx < BB * 20)  { c3[idx] = cb3[idx % 20]; return; }
}

// out[m] = sum_k relu(c3[m,k])*fW[k] + fb
__global__ __launch_bounds__(64)
void final_kernel(const float* __restrict__ c3,
                  const float* __restrict__ fW,
                  const float* __restrict__ fb,
                  float* __restrict__ out)
{
    int m = blockIdx.x * 64 + threadIdx.x;
    if (m >= BB) return;
    float acc = fb[0];
#pragma unroll
    for (int k = 0; k < 20; ++k)
        acc = fmaf(fmaxf(c3[m * 20 + k], 0.f), fW[k], acc);
    out[m] = acc;
}

extern "C" void kernel_launch(void* const* d_in, const int* in_sizes, int n_in,
                              void* d_out, int out_size, void* d_ws, size_t ws_size,
                              hipStream_t stream)
{
    const float* x   = (const float*)d_in[0];
    const float* x2  = (const float*)d_in[1];
    const float* W1  = (const float*)d_in[2];
    const float* b1  = (const float*)d_in[3];
    const float* W2  = (const float*)d_in[4];
    const float* b2  = (const float*)d_in[5];
    const float* W3  = (const float*)d_in[6];
    const float* b3  = (const float*)d_in[7];
    const float* W4  = (const float*)d_in[8];
    const float* b4  = (const float*)d_in[9];
    const float* lW1 = (const float*)d_in[10];
    const float* lb1 = (const float*)d_in[11];
    const float* lW2 = (const float*)d_in[12];
    const float* lb2 = (const float*)d_in[13];
    const float* lW3 = (const float*)d_in[14];
    const float* lb3 = (const float*)d_in[15];
    const float* cW1 = (const float*)d_in[16];
    const float* cb1 = (const float*)d_in[17];
    const float* cW2 = (const float*)d_in[18];
    const float* cb2 = (const float*)d_in[19];
    const float* cW3 = (const float*)d_in[20];
    const float* cb3 = (const float*)d_in[21];
    const float* fW  = (const float*)d_in[22];
    const float* fb  = (const float*)d_in[23];
    float* out = (float*)d_out;

    float* ws = (float*)d_ws;
    const long n_h1   = (long)BB * 3 * 119 * PP;
    const long n_h2   = (long)BB * 3 * 37 * PP;
    const long n_h3   = (long)BB * 3 * 10 * PP;
    const long n_cbuf = (long)BB * 1297;
    float* h1   = ws;
    float* h2   = h1 + n_h1;
    float* h3   = h2 + n_h2;
    float* cbuf = h3 + n_h3;
    float* e1   = cbuf + n_cbuf;
    float* e2   = e1 + (long)BB * 700;
    float* c1   = e2 + (long)BB * 200;
    float* c2   = c1 + (long)BB * 500;
    float* c3b  = c2 + (long)BB * 100;

    const int nblk = (BB * PP) / 256;   // 399

    // seed bias into all atomic-GEMM outputs (414720 elements)
    init_bias<<<1620, 256, 0, stream>>>(e1, lb1, e2, lb2, cbuf + 1197, lb3,
                                        c1, cb1, c2, cb2, c3b, cb3);

    // conv stages (T-segmented for occupancy)
    conv_pool_kernel<1, 365, 119><<<dim3(nblk, 3), 256, 0, stream>>>(x,  W1, b1, h1, 3 * 119 * PP, 40);
    conv_pool_kernel<3, 119,  37><<<dim3(nblk, 2), 256, 0, stream>>>(h1, W2, b2, h2, 3 * 37 * PP, 19);
    conv_pool_kernel<3,  37,  10><<<dim3(nblk, 1), 256, 0, stream>>>(h2, W3, b3, h3, 3 * 10 * PP, 10);
    conv_pool_kernel<3,  10,   1><<<dim3(nblk, 1), 256, 0, stream>>>(h3, W4, b4, cbuf, 1297, 1);

    // enc2 path (ReLU applied on consumer's A-load)
    gemm_atomic<0><<<dim3(22, 8, 6), 256, 0, stream>>>(x2, lW1, e1, 1307, 700, 1307, 700, 256);
    gemm_atomic<1><<<dim3( 7, 8, 3), 256, 0, stream>>>(e1, lW2, e2,  700, 200,  700, 200, 256);
    gemm_atomic<1><<<dim3( 4, 8, 1), 256, 0, stream>>>(e2, lW3, cbuf + 1197, 200, 100, 200, 1297, 256);

    // combined head
    gemm_atomic<0><<<dim3(16, 8, 6), 256, 0, stream>>>(cbuf, cW1, c1, 1297, 500, 1297, 500, 256);
    gemm_atomic<1><<<dim3( 4, 8, 2), 256, 0, stream>>>(c1, cW2, c2, 500, 100, 500, 100, 256);
    gemm_atomic<1><<<dim3( 1, 8, 1), 256, 0, stream>>>(c2, cW3, c3b, 100, 20, 100, 20, 256);

    final_kernel<<<dim3(4), 64, 0, stream>>>(c3b, fW, fb, out);
}

// Round 4
// 266.595 us; speedup vs baseline: 2.0534x; 1.1390x over previous
//
#include <hip/hip_runtime.h>

#define PP 399
#define BB 256

// ---------------------------------------------------------------------------
// Streaming conv+relu+maxpool stage state machine (per (b,p) column).
// Window j covers conv outputs [3j, 3j+9]; emitted when conv t=3j+9 arrives.
// ---------------------------------------------------------------------------
template<int CIN>
struct Stage {
    float w[3][CIN][5];
    float b[3];
    float xw[CIN][5];
    float m1[3], m2[3], m3[3];
    int nin, nout;
};

template<int CIN>
__device__ __forceinline__ void stage_reset(Stage<CIN>& s) {
#pragma unroll
    for (int ci = 0; ci < CIN; ++ci)
#pragma unroll
        for (int k = 0; k < 5; ++k) s.xw[ci][k] = 0.f;
#pragma unroll
    for (int co = 0; co < 3; ++co) { s.m1[co] = -1e30f; s.m2[co] = -1e30f; s.m3[co] = -1e30f; }
    s.nin = 0; s.nout = 0;
}

__device__ __forceinline__ void init_s1(Stage<1>& s, const float* __restrict__ Wt,
                                        const float* __restrict__ Bs, int p) {
    const float* wp = Wt + (long)p * 15;   // W1: [P][3][1][5] -> 15 floats/p
#pragma unroll
    for (int co = 0; co < 3; ++co)
#pragma unroll
        for (int k = 0; k < 5; ++k) s.w[co][0][k] = wp[co * 5 + k];
#pragma unroll
    for (int co = 0; co < 3; ++co) s.b[co] = Bs[(long)p * 3 + co];
    stage_reset(s);
}

__device__ __forceinline__ void init_s3(Stage<3>& s, const float* __restrict__ Wt,
                                        const float* __restrict__ Bs, int p) {
    const float* wp = Wt + (long)p * 45;   // W2/3/4: [P][3][3][5] -> 45 floats/p
#pragma unroll
    for (int co = 0; co < 3; ++co)
#pragma unroll
        for (int ci = 0; ci < 3; ++ci)
#pragma unroll
            for (int k = 0; k < 5; ++k)
                s.w[co][ci][k] = wp[(co * 3 + ci) * 5 + k];
#pragma unroll
    for (int co = 0; co < 3; ++co) s.b[co] = Bs[(long)p * 3 + co];
    stage_reset(s);
}

// feed one input element (CIN channels); returns true if a pooled window is
// emitted into out[3]. All control state is thread-uniform -> scalar branches.
template<int CIN>
__device__ __forceinline__ bool feed(Stage<CIN>& s, const float* in, float* out) {
#pragma unroll
    for (int ci = 0; ci < CIN; ++ci) {
        s.xw[ci][0] = s.xw[ci][1];
        s.xw[ci][1] = s.xw[ci][2];
        s.xw[ci][2] = s.xw[ci][3];
        s.xw[ci][3] = s.xw[ci][4];
        s.xw[ci][4] = in[ci];
    }
    int t = s.nin - 2;   // conv position computed by this feed
    s.nin++;
    if (t < 0) return false;

    float c[3];
#pragma unroll
    for (int co = 0; co < 3; ++co) {
        float a = s.b[co];
#pragma unroll
        for (int ci = 0; ci < CIN; ++ci)
#pragma unroll
            for (int k = 0; k < 5; ++k)
                a = fmaf(s.xw[ci][k], s.w[co][ci][k], a);
        c[co] = fmaxf(a, 0.f);
    }

    bool emit = false;
    int ph = t % 3;
    if (ph == 0) {
        if (t >= 9) {
#pragma unroll
            for (int co = 0; co < 3; ++co) out[co] = fmaxf(s.m1[co], c[co]);
            emit = true;
        }
#pragma unroll
        for (int co = 0; co < 3; ++co) {
            float a = fmaxf(s.m2[co], c[co]);
            float bb = fmaxf(s.m3[co], c[co]);
            s.m1[co] = a; s.m2[co] = bb; s.m3[co] = c[co];
        }
    } else {
#pragma unroll
        for (int co = 0; co < 3; ++co) {
            s.m1[co] = fmaxf(s.m1[co], c[co]);
            s.m2[co] = fmaxf(s.m2[co], c[co]);
            s.m3[co] = fmaxf(s.m3[co], c[co]);
        }
    }
    return emit;
}

// ---------------------------------------------------------------------------
// Fused stage1+stage2: x [256][365][399] -> h2 [256][3][37][399]
// ---------------------------------------------------------------------------
__global__ __launch_bounds__(64)
void conv_s12(const float* __restrict__ x,
              const float* __restrict__ W1, const float* __restrict__ b1,
              const float* __restrict__ W2, const float* __restrict__ b2,
              float* __restrict__ h2)
{
    int gid = blockIdx.x * 64 + threadIdx.x;
    if (gid >= BB * PP) return;
    int b = gid / PP;
    int p = gid - b * PP;

    Stage<1> s1; Stage<3> s2;
    init_s1(s1, W1, b1, p);
    init_s3(s2, W2, b2, p);

    const float* inp = x + (long)b * 365 * PP + p;
    float* o2 = h2 + (long)b * (3 * 37 * PP) + p;

    float v1[3], v2[3];
    float xs[3], xn[3];

#pragma unroll
    for (int u = 0; u < 3; ++u) xs[u] = inp[(long)u * PP];

    for (int ig = 0; ig < 123; ++ig) {          // 123*3 = 369 >= 367 feeds
        // prefetch next group
#pragma unroll
        for (int u = 0; u < 3; ++u) {
            int i = 3 * (ig + 1) + u;
            xn[u] = (i < 365) ? inp[(long)i * PP] : 0.f;
        }
#pragma unroll
        for (int u = 0; u < 3; ++u) {
            int i = 3 * ig + u;
            if (i < 367) {
                if (feed(s1, &xs[u], v1)) {
                    if (feed(s2, v1, v2)) {
                        int j = s2.nout++;
#pragma unroll
                        for (int co = 0; co < 3; ++co)
                            o2[(long)(co * 37 + j) * PP] = v2[co];
                    }
                }
            }
        }
        xs[0] = xn[0]; xs[1] = xn[1]; xs[2] = xn[2];
    }
    // flush stage2 (2 zero pads)
    float z[3] = {0.f, 0.f, 0.f};
    for (int r = 0; r < 2; ++r) {
        if (feed(s2, z, v2)) {
            int j = s2.nout++;
#pragma unroll
            for (int co = 0; co < 3; ++co)
                o2[(long)(co * 37 + j) * PP] = v2[co];
        }
    }
}

// ---------------------------------------------------------------------------
// Fused stage3+stage4: h2 [256][3][37][399] -> cbuf[b*1297 + co*399 + p]
// ---------------------------------------------------------------------------
__global__ __launch_bounds__(64)
void conv_s34(const float* __restrict__ h2,
              const float* __restrict__ W3, const float* __restrict__ b3,
              const float* __restrict__ W4, const float* __restrict__ b4,
              float* __restrict__ cbuf)
{
    int gid = blockIdx.x * 64 + threadIdx.x;
    if (gid >= BB * PP) return;
    int b = gid / PP;
    int p = gid - b * PP;

    Stage<3> s3, s4;
    init_s3(s3, W3, b3, p);
    init_s3(s4, W4, b4, p);

    const float* inp = h2 + (long)b * (3 * 37 * PP) + p;
    float* o4 = cbuf + (long)b * 1297 + p;

    float v3[3], v4[3];
    float z[3] = {0.f, 0.f, 0.f};

    for (int i = 0; i < 39; ++i) {              // 37 real + 2 pads
        float in3[3];
#pragma unroll
        for (int ci = 0; ci < 3; ++ci)
            in3[ci] = (i < 37) ? inp[(long)(ci * 37 + i) * PP] : 0.f;
        if (feed(s3, in3, v3)) {
            if (feed(s4, v3, v4)) {
#pragma unroll
                for (int co = 0; co < 3; ++co) o4[co * PP] = v4[co];
            }
        }
    }
    // flush s4 (2 zero pads)
    for (int r = 0; r < 2; ++r) {
        if (feed(s4, z, v4)) {
#pragma unroll
            for (int co = 0; co < 3; ++co) o4[co * PP] = v4[co];
        }
    }
}

// ---------------------------------------------------------------------------
// Split-K GEMM with f32 atomic accumulation. out pre-seeded with bias.
// ---------------------------------------------------------------------------
template<int RELU_A>
__global__ __launch_bounds__(256)
void gemm_atomic(const float* __restrict__ A,
                 const float* __restrict__ Wt,
                 float* __restrict__ out,
                 int K, int N, int lda, int ldo, int kchunk)
{
    __shared__ float As[32][36];
    __shared__ float Bs[32][36];

    int tid = threadIdx.x;
    int ty  = tid >> 3;
    int tx4 = (tid & 7) * 4;
    int c0 = blockIdx.x * 32;
    int m0 = blockIdx.y * 32;
    int k0 = blockIdx.z * kchunk;
    int klim = min(K, k0 + kchunk);

    float4 acc = make_float4(0.f, 0.f, 0.f, 0.f);

    for (int kb = k0; kb < klim; kb += 32) {
#pragma unroll
        for (int j = 0; j < 4; ++j) {
            int kk = kb + tx4 + j;
            float v = (kk < klim) ? A[(long)(m0 + ty) * lda + kk] : 0.f;
            if (RELU_A) v = fmaxf(v, 0.f);
            As[ty][tx4 + j] = v;
        }
#pragma unroll
        for (int j = 0; j < 4; ++j) {
            int kk = kb + ty;
            int c = c0 + tx4 + j;
            Bs[ty][tx4 + j] = (kk < klim && c < N) ? Wt[(long)kk * N + c] : 0.f;
        }
        __syncthreads();
#pragma unroll
        for (int kk = 0; kk < 32; ++kk) {
            float a = As[ty][kk];
            float4 bv = *(const float4*)&Bs[kk][tx4];
            acc.x = fmaf(a, bv.x, acc.x);
            acc.y = fmaf(a, bv.y, acc.y);
            acc.z = fmaf(a, bv.z, acc.z);
            acc.w = fmaf(a, bv.w, acc.w);
        }
        __syncthreads();
    }

    long m = m0 + ty;
    if (c0 + tx4 + 0 < N) atomicAdd(&out[m * ldo + c0 + tx4 + 0], acc.x);
    if (c0 + tx4 + 1 < N) atomicAdd(&out[m * ldo + c0 + tx4 + 1], acc.y);
    if (c0 + tx4 + 2 < N) atomicAdd(&out[m * ldo + c0 + tx4 + 2], acc.z);
    if (c0 + tx4 + 3 < N) atomicAdd(&out[m * ldo + c0 + tx4 + 3], acc.w);
}

__global__ __launch_bounds__(256)
void init_bias(float* __restrict__ e1, const float* __restrict__ lb1,
               float* __restrict__ e2, const float* __restrict__ lb2,
               float* __restrict__ enc2, const float* __restrict__ lb3,
               float* __restrict__ c1, const float* __restrict__ cb1,
               float* __restrict__ c2, const float* __restrict__ cb2,
               float* __restrict__ c3, const float* __restrict__ cb3)
{
    int idx = blockIdx.x * 256 + threadIdx.x;
    if (idx < BB * 700) { e1[idx] = lb1[idx % 700]; return; }
    idx -= BB * 700;
    if (idx < BB * 200) { e2[idx] = lb2[idx % 200]; return; }
    idx -= BB * 200;
    if (idx < BB * 100) { int m = idx / 100, c = idx % 100; enc2[(long)m * 1297 + c] = lb3[c]; return; }
    idx -= BB * 100;
    if (idx < BB * 500) { c1[idx] = cb1[idx % 500]; return; }
    idx -= BB * 500;
    if (idx < BB * 100) { c2[idx] = cb2[idx % 100]; return; }
    idx -= BB * 100;
    if (idx < BB * 20)  { c3[idx] = cb3[idx % 20]; return; }
}

__global__ __launch_bounds__(64)
void final_kernel(const float* __restrict__ c3,
                  const float* __restrict__ fW,
                  const float* __restrict__ fb,
                  float* __restrict__ out)
{
    int m = blockIdx.x * 64 + threadIdx.x;
    if (m >= BB) return;
    float acc = fb[0];
#pragma unroll
    for (int k = 0; k < 20; ++k)
        acc = fmaf(fmaxf(c3[m * 20 + k], 0.f), fW[k], acc);
    out[m] = acc;
}

extern "C" void kernel_launch(void* const* d_in, const int* in_sizes, int n_in,
                              void* d_out, int out_size, void* d_ws, size_t ws_size,
                              hipStream_t stream)
{
    const float* x   = (const float*)d_in[0];
    const float* x2  = (const float*)d_in[1];
    const float* W1  = (const float*)d_in[2];
    const float* b1  = (const float*)d_in[3];
    const float* W2  = (const float*)d_in[4];
    const float* b2  = (const float*)d_in[5];
    const float* W3  = (const float*)d_in[6];
    const float* b3  = (const float*)d_in[7];
    const float* W4  = (const float*)d_in[8];
    const float* b4  = (const float*)d_in[9];
    const float* lW1 = (const float*)d_in[10];
    const float* lb1 = (const float*)d_in[11];
    const float* lW2 = (const float*)d_in[12];
    const float* lb2 = (const float*)d_in[13];
    const float* lW3 = (const float*)d_in[14];
    const float* lb3 = (const float*)d_in[15];
    const float* cW1 = (const float*)d_in[16];
    const float* cb1 = (const float*)d_in[17];
    const float* cW2 = (const float*)d_in[18];
    const float* cb2 = (const float*)d_in[19];
    const float* cW3 = (const float*)d_in[20];
    const float* cb3 = (const float*)d_in[21];
    const float* fW  = (const float*)d_in[22];
    const float* fb  = (const float*)d_in[23];
    float* out = (float*)d_out;

    float* ws = (float*)d_ws;
    const long n_h2   = (long)BB * 3 * 37 * PP;
    const long n_cbuf = (long)BB * 1297;
    float* h2   = ws;
    float* cbuf = h2 + n_h2;
    float* e1   = cbuf + n_cbuf;
    float* e2   = e1 + (long)BB * 700;
    float* c1   = e2 + (long)BB * 200;
    float* c2   = c1 + (long)BB * 500;
    float* c3b  = c2 + (long)BB * 100;

    // seed bias into all atomic-GEMM outputs
    init_bias<<<1620, 256, 0, stream>>>(e1, lb1, e2, lb2, cbuf + 1197, lb3,
                                        c1, cb1, c2, cb2, c3b, cb3);

    // fused conv chains: (BB*PP)/64 = 1596 blocks
    conv_s12<<<1596, 64, 0, stream>>>(x, W1, b1, W2, b2, h2);
    conv_s34<<<1596, 64, 0, stream>>>(h2, W3, b3, W4, b4, cbuf);

    // enc2 path (ReLU applied on consumer's A-load)
    gemm_atomic<0><<<dim3(22, 8, 6), 256, 0, stream>>>(x2, lW1, e1, 1307, 700, 1307, 700, 256);
    gemm_atomic<1><<<dim3( 7, 8, 3), 256, 0, stream>>>(e1, lW2, e2,  700, 200,  700, 200, 256);
    gemm_atomic<1><<<dim3( 4, 8, 1), 256, 0, stream>>>(e2, lW3, cbuf + 1197, 200, 100, 200, 1297, 256);

    // combined head
    gemm_atomic<0><<<dim3(16, 8, 6), 256, 0, stream>>>(cbuf, cW1, c1, 1297, 500, 1297, 500, 256);
    gemm_atomic<1><<<dim3( 4, 8, 2), 256, 0, stream>>>(c1, cW2, c2, 500, 100, 500, 100, 256);
    gemm_atomic<1><<<dim3( 1, 8, 1), 256, 0, stream>>>(c2, cW3, c3b, 100, 20, 100, 20, 256);

    final_kernel<<<dim3(4), 64, 0, stream>>>(c3b, fW, fb, out);
}